// Round 1
// baseline (119.808 us; speedup 1.0000x reference)
//
#include <hip/hip_runtime.h>
#include <cmath>

#define IMG_H 1024
#define IMG_W 1024

// Gaussian 7x7 kernel passed by value (lands in kernarg SGPR-loaded memory;
// fully-unrolled loops index it with compile-time constants -> s_load).
struct KTab { float k[49]; };

__global__ __launch_bounds__(256)
void mind_main(const float* __restrict__ img1, const float* __restrict__ img2,
               float* __restrict__ partials, KTab kt)
{
    const int x = 7 + (int)blockIdx.x * 64 + (int)threadIdx.x;  // col in [7,1016]
    const int y = 7 + (int)blockIdx.y * 4  + (int)threadIdx.y;  // row in [7,1017]
    const bool active = (x <= 1016) && (y <= 1017);

    float T0 = 0.f;                     // blur(a^2)   (the 72 far shifts + base)
    float Ph = 0.f, Qh = 0.f;           // horizontal shift corrections (+1,0)/(-1,0)
    float Pv = 0.f, Qv = 0.f;           // vertical   shift corrections (0,+1)/(0,-1)
    float Ppp = 0.f, Pmp = 0.f, Ppm = 0.f, Pmm = 0.f;  // 4 diagonal corrections
    float V4 = 0.f;                     // 4 * (Vimg - eps)

    if (active) {
        #pragma unroll
        for (int ky = 0; ky < 7; ++ky) {
            const int yy = y + ky - 3;          // in [4,1020] -> always in bounds
            const int yp = yy ^ 512;            // the (only) valid vertical shift source
            const float* __restrict__ r2  = img2 + yy * IMG_W;
            const float* __restrict__ r2p = img2 + yp * IMG_W;
            const float* __restrict__ r1  = img1 + yy * IMG_W;
            const float* __restrict__ r1p = img1 + yp * IMG_W;
            const bool ylo = (yy & 512) == 0;   // true -> shift ty=+1 is the valid one
            #pragma unroll
            for (int kx = 0; kx < 7; ++kx) {
                const int xx = x + kx - 3;      // in [4,1019]
                const int xp = xx ^ 512;
                const bool xlo = (xx & 512) == 0;
                const float w = kt.k[ky * 7 + kx];

                // ---- img2 terms (D2 maps) ----
                const float a = r2[xx];
                const float b = r2[xp];
                const float c = r2p[xx];
                const float d = r2p[xp];
                const float a2 = a * a;
                const float tb = a - b, tc = a - c, td = a - d;
                const float dh = fmaf(tb, tb, -a2);   // (a-b)^2 - a^2
                const float dv = fmaf(tc, tc, -a2);
                const float dd = fmaf(td, td, -a2);
                T0 = fmaf(w, a2, T0);
                const float wh = w * dh, wv = w * dv, wd = w * dd;
                Ph += xlo ? wh : 0.f;   Qh += xlo ? 0.f : wh;
                Pv += ylo ? wv : 0.f;   Qv += ylo ? 0.f : wv;
                Ppp += ( xlo &&  ylo) ? wd : 0.f;   // shift (+1,+1) valid quadrant
                Pmp += (!xlo &&  ylo) ? wd : 0.f;   // shift (-1,+1)
                Ppm += ( xlo && !ylo) ? wd : 0.f;   // shift (+1,-1)
                Pmm += (!xlo && !ylo) ? wd : 0.f;   // shift (-1,-1)

                // ---- img1 terms (Vimg): sum over SHIFTS4, no predicates needed ----
                const float u  = r1[xx];
                const float ub = r1[xp];
                const float uc = r1p[xx];
                const float su = u - ub, sv = u - uc;
                const float t1 = fmaf(u, u + u, fmaf(su, su, sv * sv));
                V4 = fmaf(w, t1, V4);
            }
        }
    }

    float pix = 0.f;
    if (active) {
        const float V = fmaf(V4, 0.25f, 1e-5f);
        const float invV = 1.0f / V;
        float M = fminf(0.f, Ph);
        M = fminf(M, Qh);  M = fminf(M, Pv);  M = fminf(M, Qv);
        M = fminf(M, Ppp); M = fminf(M, Pmp); M = fminf(M, Ppm); M = fminf(M, Pmm);
        // pixel contribution: sum_s exp(-(D_s - Dmin)/V), with multiplicity 72 for T0
        pix = 72.f * __expf(M * invV)
            + __expf((M - Ph ) * invV) + __expf((M - Qh ) * invV)
            + __expf((M - Pv ) * invV) + __expf((M - Qv ) * invV)
            + __expf((M - Ppp) * invV) + __expf((M - Pmp) * invV)
            + __expf((M - Ppm) * invV) + __expf((M - Pmm) * invV);
    }

    // block reduction: wave shuffle then LDS across the 4 waves
    float v = pix;
    #pragma unroll
    for (int off = 32; off > 0; off >>= 1)
        v += __shfl_down(v, off, 64);
    __shared__ float wsum[4];
    if (threadIdx.x == 0) wsum[threadIdx.y] = v;   // blockDim=(64,4): wave id == ty
    __syncthreads();
    if (threadIdx.x == 0 && threadIdx.y == 0) {
        const int bid = (int)blockIdx.y * gridDim.x + (int)blockIdx.x;
        partials[bid] = wsum[0] + wsum[1] + wsum[2] + wsum[3];
    }
}

__global__ __launch_bounds__(256)
void mind_reduce(const float* __restrict__ partials, int n, float* __restrict__ out)
{
    double s = 0.0;
    for (int i = (int)threadIdx.x; i < n; i += 256) s += (double)partials[i];
    #pragma unroll
    for (int off = 32; off > 0; off >>= 1)
        s += __shfl_down(s, off, 64);
    __shared__ double sm[4];
    const int lane = (int)threadIdx.x & 63;
    const int wid  = (int)threadIdx.x >> 6;
    if (lane == 0) sm[wid] = s;
    __syncthreads();
    if (threadIdx.x == 0) {
        const double t = sm[0] + sm[1] + sm[2] + sm[3];
        out[0] = (float)(t / 81688800.0);   // 80 * 1011 * 1010
    }
}

extern "C" void kernel_launch(void* const* d_in, const int* in_sizes, int n_in,
                              void* d_out, int out_size, void* d_ws, size_t ws_size,
                              hipStream_t stream) {
    const float* img1 = (const float*)d_in[0];
    const float* img2 = (const float*)d_in[1];
    float* out = (float*)d_out;
    float* partials = (float*)d_ws;

    KTab kt;
    for (int i = 0; i < 7; ++i)
        for (int j = 0; j < 7; ++j) {
            const double dy = i - 3, dx = j - 3;
            kt.k[i * 7 + j] = (float)(std::exp(-(dy * dy + dx * dx) / 8.0) / (8.0 * M_PI));
        }

    dim3 block(64, 4);
    dim3 grid(16, 253);   // 16*64=1024 >= 1010 cols ; 253*4=1012 >= 1011 rows
    mind_main<<<grid, block, 0, stream>>>(img1, img2, partials, kt);
    mind_reduce<<<1, 256, 0, stream>>>(partials, 16 * 253, out);
}

// Round 2
// 80.759 us; speedup vs baseline: 1.4835x; 1.4835x over previous
//
#include <hip/hip_runtime.h>
#include <cmath>

#define IMG_W 1024
#define TW 64     // tile output width
#define TH 16     // tile output height
#define PW 70     // padded width  (TW + 6)
#define PH 22     // padded height (TH + 6)

// separable Gaussian: w(ky,kx) = gv[ky] * gh[kx], 1/(8*pi) folded into gv
struct GK { float gh[7]; float gv[7]; };

__global__ __launch_bounds__(256)
void mind_fused(const float* __restrict__ img1, const float* __restrict__ img2,
                float* __restrict__ out, GK gk)
{
    __shared__ float s1[4][PH][PW];   // pointwise fields: H, V, D, U   (24640 B)
    __shared__ float s2[6][PH][TW];   // hHlo,hHhi,hV,hDlo,hDhi,hU      (33792 B)

    const int tx = (int)threadIdx.x;   // 0..63
    const int ty = (int)threadIdx.y;   // 0..3
    const int x0 = 7 + (int)blockIdx.x * TW;   // first output col of tile
    const int y0 = 7 + (int)blockIdx.y * TH;   // first output row of tile

    // ---- stage 1: pointwise fields over the padded tile ----
    // H(p) = (a - a_xshift)^2 - a^2 ; V, D likewise for y / diagonal shift.
    // U(p) = 2u^2 + (u - u_xshift)^2 + (u - u_yshift)^2   (Vimg*4 integrand)
    #pragma unroll
    for (int k = 0; k < 6; ++k) {
        const int r = 4 * k + ty;
        if (r < PH) {
            const int yy = min(y0 - 3 + r, 1023);
            const int yp = yy ^ 512;                  // only valid vertical shift source
            const float* __restrict__ r2  = img2 + yy * IMG_W;
            const float* __restrict__ r2p = img2 + yp * IMG_W;
            const float* __restrict__ r1  = img1 + yy * IMG_W;
            const float* __restrict__ r1p = img1 + yp * IMG_W;
            #pragma unroll
            for (int h = 0; h < 2; ++h) {
                const int c = tx + 64 * h;
                if (h == 0 || tx < PW - 64) {
                    const int xx = min(x0 - 3 + c, 1023);
                    const int xp = xx ^ 512;
                    const float a = r2[xx], b = r2[xp], cc = r2p[xx], d = r2p[xp];
                    const float a2 = a * a;
                    const float tb = a - b, tc = a - cc, td = a - d;
                    s1[0][r][c] = fmaf(tb, tb, -a2);
                    s1[1][r][c] = fmaf(tc, tc, -a2);
                    s1[2][r][c] = fmaf(td, td, -a2);
                    const float u = r1[xx], ub = r1[xp], uc = r1p[xx];
                    const float su = u - ub, sv = u - uc;
                    s1[3][r][c] = fmaf(u, u + u, fmaf(su, su, sv * sv));
                }
            }
        }
    }
    __syncthreads();

    // ---- stage 2: horizontal 7-tap conv, splitting H and D by x-mask ----
    #pragma unroll
    for (int k = 0; k < 6; ++k) {
        const int r = 4 * k + ty;
        if (r < PH) {
            float hlo = 0, hhi = 0, hv = 0, dlo = 0, dhi = 0, hu = 0;
            #pragma unroll
            for (int kx = 0; kx < 7; ++kx) {
                const float g = gk.gh[kx];
                const bool lo = (((x0 - 3 + tx + kx) & 512) == 0);
                const float gl  = lo ? g : 0.f;
                const float gh_ = lo ? 0.f : g;
                const float Hv = s1[0][r][tx + kx];
                const float Vv = s1[1][r][tx + kx];
                const float Dv = s1[2][r][tx + kx];
                const float Uv = s1[3][r][tx + kx];
                hlo = fmaf(gl,  Hv, hlo);
                hhi = fmaf(gh_, Hv, hhi);
                hv  = fmaf(g,   Vv, hv);
                dlo = fmaf(gl,  Dv, dlo);
                dhi = fmaf(gh_, Dv, dhi);
                hu  = fmaf(g,   Uv, hu);
            }
            s2[0][r][tx] = hlo; s2[1][r][tx] = hhi; s2[2][r][tx] = hv;
            s2[3][r][tx] = dlo; s2[4][r][tx] = dhi; s2[5][r][tx] = hu;
        }
    }
    __syncthreads();

    // ---- stage 3: vertical conv (y-mask is wave-uniform) + exp epilogue ----
    // each thread handles 4 consecutive output rows; cache its 10 needed s2 rows
    float f0[10], f1[10], f2[10], f3[10], f4[10], f5[10];
    #pragma unroll
    for (int r = 0; r < 10; ++r) {
        const int rr = 4 * ty + r;
        f0[r] = s2[0][rr][tx]; f1[r] = s2[1][rr][tx]; f2[r] = s2[2][rr][tx];
        f3[r] = s2[3][rr][tx]; f4[r] = s2[4][rr][tx]; f5[r] = s2[5][rr][tx];
    }

    const int xo = x0 + tx;
    float tsum = 0.f;
    #pragma unroll
    for (int k = 0; k < 4; ++k) {
        const int i  = 4 * ty + k;     // local output row
        const int yo = y0 + i;
        float Ph = 0, Qh = 0, Pv = 0, Qv = 0, Ppp = 0, Pmp = 0, Ppm = 0, Pmm = 0, V4 = 0;
        #pragma unroll
        for (int ky = 0; ky < 7; ++ky) {
            const float g = gk.gv[ky];
            const bool ylo = (((yo - 3 + ky) & 512) == 0);
            const float wl = ylo ? g : 0.f;
            const float wh = ylo ? 0.f : g;
            const int idx = k + ky;
            Ph  = fmaf(g,  f0[idx], Ph);
            Qh  = fmaf(g,  f1[idx], Qh);
            Pv  = fmaf(wl, f2[idx], Pv);
            Qv  = fmaf(wh, f2[idx], Qv);
            Ppp = fmaf(wl, f3[idx], Ppp);
            Ppm = fmaf(wh, f3[idx], Ppm);
            Pmp = fmaf(wl, f4[idx], Pmp);
            Pmm = fmaf(wh, f4[idx], Pmm);
            V4  = fmaf(g,  f5[idx], V4);
        }
        const float V = fmaf(V4, 0.25f, 1e-5f);
        const float invV = 1.0f / V;
        float M = fminf(0.f, Ph);
        M = fminf(M, Qh);  M = fminf(M, Pv);  M = fminf(M, Qv);
        M = fminf(M, Ppp); M = fminf(M, Pmp); M = fminf(M, Ppm); M = fminf(M, Pmm);
        const float pix = 72.f * __expf(M * invV)
            + __expf((M - Ph ) * invV) + __expf((M - Qh ) * invV)
            + __expf((M - Pv ) * invV) + __expf((M - Qv ) * invV)
            + __expf((M - Ppp) * invV) + __expf((M - Pmp) * invV)
            + __expf((M - Ppm) * invV) + __expf((M - Pmm) * invV);
        const bool active = (xo <= 1016) && (yo <= 1017);
        tsum += active ? pix : 0.f;   // cndmask: NaN/Inf in inactive lanes discarded
    }

    // ---- block reduction + one atomic per block ----
    #pragma unroll
    for (int off = 32; off > 0; off >>= 1)
        tsum += __shfl_down(tsum, off, 64);
    __shared__ float wsum[4];
    if (tx == 0) wsum[ty] = tsum;
    __syncthreads();
    if (tx == 0 && ty == 0) {
        const float bt = wsum[0] + wsum[1] + wsum[2] + wsum[3];
        atomicAdd(out, bt * (1.0f / 81688800.0f));   // 80 * 1011 * 1010
    }
}

extern "C" void kernel_launch(void* const* d_in, const int* in_sizes, int n_in,
                              void* d_out, int out_size, void* d_ws, size_t ws_size,
                              hipStream_t stream) {
    const float* img1 = (const float*)d_in[0];
    const float* img2 = (const float*)d_in[1];
    float* out = (float*)d_out;

    GK gk;
    for (int i = 0; i < 7; ++i) {
        const double d = i - 3;
        gk.gh[i] = (float)std::exp(-(d * d) / 8.0);
        gk.gv[i] = (float)(std::exp(-(d * d) / 8.0) / (8.0 * M_PI));
    }

    hipMemsetAsync(d_out, 0, sizeof(float), stream);
    dim3 block(64, 4);
    dim3 grid(16, 64);   // 16*64=1024 >= 1010 cols ; 64*16=1024 >= 1011 rows
    mind_fused<<<grid, block, 0, stream>>>(img1, img2, out, gk);
}